// Round 1
// baseline (803.447 us; speedup 1.0000x reference)
//
#include <hip/hip_runtime.h>
#include <math.h>

#define EPS 1e-5f
#define NPOINT 4096
#define KNBR 128
#define NPK (NPOINT * KNBR)   // 524288 pixels

// Workspace layout (floats): BN-folded weights & biases
//   A1[64*3] C1[64] A2[64*64] C2[64] A3[128*64] C3[128]
#define OFF_A1 0
#define OFF_C1 (OFF_A1 + 64 * 3)
#define OFF_A2 (OFF_C1 + 64)
#define OFF_C2 (OFF_A2 + 64 * 64)
#define OFF_A3 (OFF_C2 + 64)
#define OFF_C3 (OFF_A3 + 128 * 64)
#define WS_FLOATS (OFF_C3 + 128)   // 12736 floats = ~51 KB

// Fold BN into conv: y = (Wx+b)*inv + (beta - mean*inv),  inv = gamma/sqrt(var+eps)
//   => A = W * inv[o],  C = b*inv + beta - mean*inv
__global__ void prep_kernel(
    const float* __restrict__ W1, const float* __restrict__ b1,
    const float* __restrict__ g1, const float* __restrict__ be1,
    const float* __restrict__ m1, const float* __restrict__ v1,
    const float* __restrict__ W2, const float* __restrict__ b2,
    const float* __restrict__ g2, const float* __restrict__ be2,
    const float* __restrict__ m2, const float* __restrict__ v2,
    const float* __restrict__ W3, const float* __restrict__ b3,
    const float* __restrict__ g3, const float* __restrict__ be3,
    const float* __restrict__ m3, const float* __restrict__ v3,
    float* __restrict__ ws)
{
    int t = blockIdx.x * blockDim.x + threadIdx.x;
    int stride = gridDim.x * blockDim.x;

    // layer 1: 64 x 3
    for (int idx = t; idx < 64 * 3; idx += stride) {
        int o = idx / 3;
        float inv = g1[o] * rsqrtf(v1[o] + EPS);
        ws[OFF_A1 + idx] = W1[idx] * inv;
    }
    for (int o = t; o < 64; o += stride) {
        float inv = g1[o] * rsqrtf(v1[o] + EPS);
        ws[OFF_C1 + o] = b1[o] * inv + be1[o] - m1[o] * inv;
    }
    // layer 2: 64 x 64
    for (int idx = t; idx < 64 * 64; idx += stride) {
        int o = idx >> 6;
        float inv = g2[o] * rsqrtf(v2[o] + EPS);
        ws[OFF_A2 + idx] = W2[idx] * inv;
    }
    for (int o = t; o < 64; o += stride) {
        float inv = g2[o] * rsqrtf(v2[o] + EPS);
        ws[OFF_C2 + o] = b2[o] * inv + be2[o] - m2[o] * inv;
    }
    // layer 3: 128 x 64
    for (int idx = t; idx < 128 * 64; idx += stride) {
        int o = idx >> 6;
        float inv = g3[o] * rsqrtf(v3[o] + EPS);
        ws[OFF_A3 + idx] = W3[idx] * inv;
    }
    for (int o = t; o < 128; o += stride) {
        float inv = g3[o] * rsqrtf(v3[o] + EPS);
        ws[OFF_C3 + o] = b3[o] * inv + be3[o] - m3[o] * inv;
    }
}

// One thread per pixel. Weights are wave-uniform -> scalar (s_load) reads via
// the constant cache; every MAC is a single v_fmac_f32 with an SGPR operand.
// h1[64] + h2[64] live in VGPRs (~150 VGPR total -> ~3 waves/SIMD).
__global__ __launch_bounds__(256) void pointnet_fused(
    const float* __restrict__ x, const float* __restrict__ valid,
    const float* __restrict__ ws, float* __restrict__ out)
{
    const int pix = blockIdx.x * 256 + threadIdx.x;

    const float x0 = x[pix];
    const float x1 = x[pix + NPK];
    const float x2 = x[pix + 2 * NPK];

    const float* __restrict__ A1 = ws + OFF_A1;
    const float* __restrict__ C1 = ws + OFF_C1;
    const float* __restrict__ A2 = ws + OFF_A2;
    const float* __restrict__ C2 = ws + OFF_C2;
    const float* __restrict__ A3 = ws + OFF_A3;
    const float* __restrict__ C3 = ws + OFF_C3;

    // layer 1: 3 -> 64
    float h1[64];
#pragma unroll
    for (int o = 0; o < 64; ++o) {
        float a = C1[o];
        a = fmaf(A1[3 * o + 0], x0, a);
        a = fmaf(A1[3 * o + 1], x1, a);
        a = fmaf(A1[3 * o + 2], x2, a);
        h1[o] = fmaxf(a, 0.0f);
    }

    // layer 2: 64 -> 64
    float h2[64];
#pragma unroll 4
    for (int o = 0; o < 64; ++o) {
        float a = C2[o];
#pragma unroll
        for (int i = 0; i < 64; ++i)
            a = fmaf(A2[o * 64 + i], h1[i], a);
        h2[o] = fmaxf(a, 0.0f);
    }

    // layer 3: 64 -> 128, mask, store (coalesced per channel)
    const float v = valid[pix];
#pragma unroll 4
    for (int o = 0; o < 128; ++o) {
        float a = C3[o];
#pragma unroll
        for (int i = 0; i < 64; ++i)
            a = fmaf(A3[o * 64 + i], h2[i], a);
        out[o * NPK + pix] = fmaxf(a, 0.0f) * v;
    }
}

extern "C" void kernel_launch(void* const* d_in, const int* in_sizes, int n_in,
                              void* d_out, int out_size, void* d_ws, size_t ws_size,
                              hipStream_t stream) {
    const float* x     = (const float*)d_in[0];
    const float* valid = (const float*)d_in[1];

    const float* W1 = (const float*)d_in[2];
    const float* b1 = (const float*)d_in[3];
    const float* g1 = (const float*)d_in[4];
    const float* be1 = (const float*)d_in[5];
    const float* m1 = (const float*)d_in[6];
    const float* v1 = (const float*)d_in[7];

    const float* W2 = (const float*)d_in[8];
    const float* b2 = (const float*)d_in[9];
    const float* g2 = (const float*)d_in[10];
    const float* be2 = (const float*)d_in[11];
    const float* m2 = (const float*)d_in[12];
    const float* v2 = (const float*)d_in[13];

    const float* W3 = (const float*)d_in[14];
    const float* b3 = (const float*)d_in[15];
    const float* g3 = (const float*)d_in[16];
    const float* be3 = (const float*)d_in[17];
    const float* m3 = (const float*)d_in[18];
    const float* v3 = (const float*)d_in[19];

    float* ws  = (float*)d_ws;
    float* out = (float*)d_out;

    prep_kernel<<<32, 256, 0, stream>>>(W1, b1, g1, be1, m1, v1,
                                        W2, b2, g2, be2, m2, v2,
                                        W3, b3, g3, be3, m3, v3, ws);

    pointnet_fused<<<NPK / 256, 256, 0, stream>>>(x, valid, ws, out);
}

// Round 2
// 358.835 us; speedup vs baseline: 2.2390x; 2.2390x over previous
//
#include <hip/hip_runtime.h>
#include <math.h>

#define EPS 1e-5f
#define NPK (4096 * 128)   // 524288 pixels

typedef __attribute__((ext_vector_type(8))) short bf16x8;   // 8 bf16 = 4 VGPRs
typedef __attribute__((ext_vector_type(4))) short short4v;  // 4 bf16 = 8 B
typedef __attribute__((ext_vector_type(4))) float f32x4;

__device__ __forceinline__ short f2bf(float f) {
    union { float f; unsigned u; } x; x.f = f;
    unsigned r = x.u + 0x7fffu + ((x.u >> 16) & 1u);   // round-to-nearest-even
    return (short)(r >> 16);
}

// ws layout (floats): A1[192] C1[64] C2[64] C3[128] | then bf16: A2b[64*64] A3b[128*64]
#define WS_A1 0
#define WS_C1 192
#define WS_C2 256
#define WS_C3 320
#define WS_BF 448   // float offset where bf16 region starts

__global__ void prep_kernel(
    const float* __restrict__ W1, const float* __restrict__ b1,
    const float* __restrict__ g1, const float* __restrict__ be1,
    const float* __restrict__ m1, const float* __restrict__ v1,
    const float* __restrict__ W2, const float* __restrict__ b2,
    const float* __restrict__ g2, const float* __restrict__ be2,
    const float* __restrict__ m2, const float* __restrict__ v2,
    const float* __restrict__ W3, const float* __restrict__ b3,
    const float* __restrict__ g3, const float* __restrict__ be3,
    const float* __restrict__ m3, const float* __restrict__ v3,
    float* __restrict__ ws)
{
    const int t = threadIdx.x;
    if (t < 64) {
        float inv1 = g1[t] * rsqrtf(v1[t] + EPS);
        ws[WS_C1 + t] = b1[t] * inv1 + be1[t] - m1[t] * inv1;
        ws[WS_A1 + t * 3 + 0] = W1[t * 3 + 0] * inv1;
        ws[WS_A1 + t * 3 + 1] = W1[t * 3 + 1] * inv1;
        ws[WS_A1 + t * 3 + 2] = W1[t * 3 + 2] * inv1;
        float inv2 = g2[t] * rsqrtf(v2[t] + EPS);
        ws[WS_C2 + t] = b2[t] * inv2 + be2[t] - m2[t] * inv2;
    }
    if (t < 128) {
        float inv3 = g3[t] * rsqrtf(v3[t] + EPS);
        ws[WS_C3 + t] = b3[t] * inv3 + be3[t] - m3[t] * inv3;
    }
    short* A2b = (short*)(ws + WS_BF);
    short* A3b = A2b + 64 * 64;
    for (int idx = t; idx < 64 * 64; idx += 256) {
        int o = idx >> 6;
        float inv = g2[o] * rsqrtf(v2[o] + EPS);
        A2b[idx] = f2bf(W2[idx] * inv);
    }
    for (int idx = t; idx < 128 * 64; idx += 256) {
        int o = idx >> 6;
        float inv = g3[o] * rsqrtf(v3[o] + EPS);
        A3b[idx] = f2bf(W3[idx] * inv);
    }
}

// One block = 256 threads = 4 waves, processes a tile of 128 pixels.
// L1 (3->64) fp32 VALU -> h1 bf16 in LDS [pixel][ch], row stride 72 (pad).
// L2 (64x64) and L3 (128x64) via mfma_f32_16x16x32_bf16.
// Fragment layouts (gfx950, HW-verified per guide):
//   A: A[m=lane&15][k=quad*8+j]   B: B[k=quad*8+j][n=lane&15]
//   C/D: col=lane&15, row=quad*4+reg
__global__ __launch_bounds__(256) void pointnet_mfma(
    const float* __restrict__ x, const float* __restrict__ valid,
    const float* __restrict__ ws, float* __restrict__ out)
{
    __shared__ short h1[128 * 72];   // 18432 B
    __shared__ short h2[128 * 72];   // 18432 B
    __shared__ float vld[128];

    const int t = threadIdx.x;
    const int pbase = blockIdx.x * 128;

    const float* __restrict__ A1 = ws + WS_A1;
    const float* __restrict__ C1 = ws + WS_C1;
    const float* __restrict__ C2 = ws + WS_C2;
    const float* __restrict__ C3 = ws + WS_C3;
    const short* __restrict__ A2b = (const short*)(ws + WS_BF);
    const short* __restrict__ A3b = A2b + 64 * 64;

    // ---- Layer 1: 3 -> 64, fp32, two threads per pixel (32 ch each) ----
    {
        const int pl = t & 127;          // local pixel
        const int half = t >> 7;         // wave-uniform (waves 0,1 -> 0; 2,3 -> 1)
        const int pg = pbase + pl;
        const float x0 = x[pg];
        const float x1 = x[pg + NPK];
        const float x2 = x[pg + 2 * NPK];
        if (half == 0) vld[pl] = valid[pg];
        const int cb = half * 32;
#pragma unroll
        for (int g = 0; g < 4; ++g) {
            bf16x8 vb;
#pragma unroll
            for (int j = 0; j < 8; ++j) {
                const int ch = cb + g * 8 + j;
                float a = C1[ch];
                a = fmaf(A1[ch * 3 + 0], x0, a);
                a = fmaf(A1[ch * 3 + 1], x1, a);
                a = fmaf(A1[ch * 3 + 2], x2, a);
                vb[j] = f2bf(fmaxf(a, 0.0f));
            }
            *(bf16x8*)&h1[pl * 72 + cb + g * 8] = vb;
        }
    }
    __syncthreads();

    const int lane = t & 63;
    const int w = t >> 6;          // wave id 0..3
    const int lanelo = lane & 15;
    const int quad = lane >> 4;

    // A fragments (loop-invariant, from L1/L2-cached weight tables)
    bf16x8 a2f[2], a3f[2][2];
#pragma unroll
    for (int ks = 0; ks < 2; ++ks)
        a2f[ks] = *(const bf16x8*)&A2b[(w * 16 + lanelo) * 64 + ks * 32 + quad * 8];
#pragma unroll
    for (int mt = 0; mt < 2; ++mt)
#pragma unroll
        for (int ks = 0; ks < 2; ++ks)
            a3f[mt][ks] = *(const bf16x8*)&A3b[((w * 2 + mt) * 16 + lanelo) * 64 + ks * 32 + quad * 8];

    // ---- Layer 2: 64x64 @ 64x128. Wave w owns rows [16w,16w+16). ----
    const f32x4 bias2 = *(const f32x4*)&C2[w * 16 + quad * 4];
#pragma unroll
    for (int nt = 0; nt < 8; ++nt) {
        const int n = nt * 16 + lanelo;
        bf16x8 b0 = *(const bf16x8*)&h1[n * 72 + 0  + quad * 8];
        bf16x8 b1 = *(const bf16x8*)&h1[n * 72 + 32 + quad * 8];
        f32x4 acc = {0.f, 0.f, 0.f, 0.f};
        acc = __builtin_amdgcn_mfma_f32_16x16x32_bf16(a2f[0], b0, acc, 0, 0, 0);
        acc = __builtin_amdgcn_mfma_f32_16x16x32_bf16(a2f[1], b1, acc, 0, 0, 0);
        short4v o;
#pragma unroll
        for (int r = 0; r < 4; ++r)
            o[r] = f2bf(fmaxf(acc[r] + bias2[r], 0.0f));
        // pixel n (col), channels w*16+quad*4 .. +3 (rows) -> contiguous 8 B
        *(short4v*)&h2[n * 72 + w * 16 + quad * 4] = o;
    }
    __syncthreads();

    // ---- Layer 3: 128x64 @ 64x128. Wave w owns rows [32w, 32w+32). ----
    f32x4 acc3[16];
#pragma unroll
    for (int i = 0; i < 16; ++i) acc3[i] = (f32x4){0.f, 0.f, 0.f, 0.f};
#pragma unroll
    for (int nt = 0; nt < 8; ++nt) {
        const int n = nt * 16 + lanelo;
        bf16x8 b0 = *(const bf16x8*)&h2[n * 72 + 0  + quad * 8];
        bf16x8 b1 = *(const bf16x8*)&h2[n * 72 + 32 + quad * 8];
#pragma unroll
        for (int mt = 0; mt < 2; ++mt) {
            acc3[mt * 8 + nt] = __builtin_amdgcn_mfma_f32_16x16x32_bf16(a3f[mt][0], b0, acc3[mt * 8 + nt], 0, 0, 0);
            acc3[mt * 8 + nt] = __builtin_amdgcn_mfma_f32_16x16x32_bf16(a3f[mt][1], b1, acc3[mt * 8 + nt], 0, 0, 0);
        }
    }

    // ---- Epilogue: bias + relu + mask + store ----
#pragma unroll
    for (int mt = 0; mt < 2; ++mt) {
        const int mrow = (w * 2 + mt) * 16 + quad * 4;
        const f32x4 bias3 = *(const f32x4*)&C3[mrow];
#pragma unroll
        for (int nt = 0; nt < 8; ++nt) {
            const float v = vld[nt * 16 + lanelo];
            const int pg = pbase + nt * 16 + lanelo;
            const f32x4 a = acc3[mt * 8 + nt];
#pragma unroll
            for (int r = 0; r < 4; ++r)
                out[(mrow + r) * NPK + pg] = fmaxf(a[r] + bias3[r], 0.0f) * v;
        }
    }
}

extern "C" void kernel_launch(void* const* d_in, const int* in_sizes, int n_in,
                              void* d_out, int out_size, void* d_ws, size_t ws_size,
                              hipStream_t stream) {
    const float* x     = (const float*)d_in[0];
    const float* valid = (const float*)d_in[1];

    const float* W1 = (const float*)d_in[2];
    const float* b1 = (const float*)d_in[3];
    const float* g1 = (const float*)d_in[4];
    const float* be1 = (const float*)d_in[5];
    const float* m1 = (const float*)d_in[6];
    const float* v1 = (const float*)d_in[7];

    const float* W2 = (const float*)d_in[8];
    const float* b2 = (const float*)d_in[9];
    const float* g2 = (const float*)d_in[10];
    const float* be2 = (const float*)d_in[11];
    const float* m2 = (const float*)d_in[12];
    const float* v2 = (const float*)d_in[13];

    const float* W3 = (const float*)d_in[14];
    const float* b3 = (const float*)d_in[15];
    const float* g3 = (const float*)d_in[16];
    const float* be3 = (const float*)d_in[17];
    const float* m3 = (const float*)d_in[18];
    const float* v3 = (const float*)d_in[19];

    float* ws  = (float*)d_ws;
    float* out = (float*)d_out;

    prep_kernel<<<1, 256, 0, stream>>>(W1, b1, g1, be1, m1, v1,
                                       W2, b2, g2, be2, m2, v2,
                                       W3, b3, g3, be3, m3, v3, ws);

    pointnet_mfma<<<NPK / 128, 256, 0, stream>>>(x, valid, ws, out);
}